// Round 2
// baseline (71.122 us; speedup 1.0000x reference)
//
#include <hip/hip_runtime.h>
#include <cfloat>

// Problem constants: N=2048 rows, D=1024, K=256 centroids, NG=512 groups.
#define NROWS    2048
#define DDIM     1024
#define KCEN     256
#define LUT_SIZE 2048   // lower-bound LUT over [-1,1]; unit vector => |v| <= 1 always

// ---------------------------------------------------------------------------
// Prep: build lut[e] = count of midpoints < grid[e], grid[e] = -1 + e*(2/LUT_SIZE).
// 8 blocks x 256 threads, one LUT entry per thread. Runs once per launch (~1 us).
// ---------------------------------------------------------------------------
__global__ __launch_bounds__(256)
void prep_lut_kernel(const float* __restrict__ cen, int* __restrict__ lut) {
    __shared__ float s_cen[KCEN];
    __shared__ float s_mid[KCEN];   // s_mid[255] = +inf pad
    const int t = threadIdx.x;
    s_cen[t] = cen[t];
    __syncthreads();
    s_mid[t] = (t < KCEN - 1) ? 0.5f * (s_cen[t] + s_cen[t + 1]) : FLT_MAX;
    __syncthreads();

    const int e = blockIdx.x * 256 + t;
    const float g = -1.0f + (float)e * (2.0f / LUT_SIZE);
    int idx = 0;
    #pragma unroll
    for (int s = 128; s >= 1; s >>= 1)
        if (s_mid[idx + s - 1] < g) idx += s;
    lut[e] = idx;
}

// ---------------------------------------------------------------------------
// Main: one block per row, 256 threads, 4 scalars (= 2 rotation pairs) each.
// ---------------------------------------------------------------------------
__global__ __launch_bounds__(256)
void planar_quant_kernel(const float* __restrict__ x,
                         const float* __restrict__ cen,
                         const float* __restrict__ rot,
                         const int*   __restrict__ lut,
                         float* __restrict__ out_xhat,
                         float* __restrict__ out_idx)
{
    __shared__ float s_cen[KCEN];
    __shared__ float s_mid[KCEN];     // s_mid[255] = +inf pad
    __shared__ int   s_lut[LUT_SIZE];
    __shared__ float s_red[4];
    __shared__ float s_norm;

    const int row = blockIdx.x;
    const int t   = threadIdx.x;

    // Stage codebook + LUT into LDS (vectorized: 2x int4 per thread for LUT).
    s_cen[t] = cen[t];
    ((int4*)s_lut)[t]       = ((const int4*)lut)[t];
    ((int4*)s_lut)[256 + t] = ((const int4*)lut)[256 + t];
    __syncthreads();
    s_mid[t] = (t < KCEN - 1) ? 0.5f * (s_cen[t] + s_cen[t + 1]) : FLT_MAX;
    // (s_mid consumed only after the norm __syncthreads below)

    // Coalesced vector loads.
    const float4 xv = *(const float4*)(x + (size_t)row * DDIM + 4 * t);
    const float4 rv = *(const float4*)(rot + 4 * t);   // (c0,s0,c1,s1)

    // Row norm: wave shuffle reduce -> cross-wave LDS.
    float ss = xv.x * xv.x + xv.y * xv.y + xv.z * xv.z + xv.w * xv.w;
    #pragma unroll
    for (int off = 32; off >= 1; off >>= 1)
        ss += __shfl_xor(ss, off, 64);
    if ((t & 63) == 0) s_red[t >> 6] = ss;
    __syncthreads();
    if (t == 0) {
        float tot = s_red[0] + s_red[1] + s_red[2] + s_red[3];
        s_norm = fmaxf(sqrtf(tot), 1e-8f);
    }
    __syncthreads();
    const float nrm = s_norm;
    const float inv = 1.0f / nrm;

    // Rotate pairs.
    float v0 = xv.x * inv, v1 = xv.y * inv, v2 = xv.z * inv, v3 = xv.w * inv;
    float r[4];
    r[0] = rv.x * v0 - rv.y * v1;
    r[1] = rv.y * v0 + rv.x * v1;
    r[2] = rv.z * v2 - rv.w * v3;
    r[3] = rv.w * v2 + rv.z * v3;

    // Quantize: LUT warm start + exact lower-bound correction + neighbor fix-up.
    int   qi[4];
    float qv[4];
    #pragma unroll
    for (int e = 0; e < 4; ++e) {
        const float v = r[e];
        int j = (int)((v + 1.0f) * (LUT_SIZE * 0.5f));
        j = min(max(j, 0), LUT_SIZE - 1);
        int idx = s_lut[j];
        // Exact lower bound (count of mids < v); loops are ~0-1 iterations.
        while (idx > 0 && s_mid[idx - 1] >= v) --idx;
        while (s_mid[idx] < v) ++idx;            // s_mid[255]=+inf guards
        // Neighbor fix-up with exact distances (argmin picks lowest index on ties).
        float best = fabsf(v - s_cen[idx]);
        if (idx > 0 && fabsf(v - s_cen[idx - 1]) <= best) {
            idx -= 1;
        } else if (idx < KCEN - 1 && fabsf(v - s_cen[idx + 1]) < best) {
            idx += 1;
        }
        qi[e] = idx;
        qv[e] = s_cen[idx];
    }

    // Inverse rotation + rescale.
    float4 xh;
    xh.x = ( rv.x * qv[0] + rv.y * qv[1]) * nrm;
    xh.y = (-rv.y * qv[0] + rv.x * qv[1]) * nrm;
    xh.z = ( rv.z * qv[2] + rv.w * qv[3]) * nrm;
    xh.w = (-rv.w * qv[2] + rv.z * qv[3]) * nrm;

    float4 fi;
    fi.x = (float)qi[0]; fi.y = (float)qi[1]; fi.z = (float)qi[2]; fi.w = (float)qi[3];

    const size_t off = (size_t)row * DDIM + 4 * t;
    *(float4*)(out_xhat + off) = xh;
    *(float4*)(out_idx  + off) = fi;
}

extern "C" void kernel_launch(void* const* d_in, const int* in_sizes, int n_in,
                              void* d_out, int out_size, void* d_ws, size_t ws_size,
                              hipStream_t stream) {
    const float* x   = (const float*)d_in[0];   // [2048*1024]
    const float* cen = (const float*)d_in[1];   // [256] sorted
    const float* rot = (const float*)d_in[2];   // [1024]
    float* out       = (float*)d_out;           // [2 * 2048*1024]
    int*   lut       = (int*)d_ws;              // 2048 ints = 8 KB scratch

    prep_lut_kernel<<<LUT_SIZE / 256, 256, 0, stream>>>(cen, lut);
    planar_quant_kernel<<<NROWS, 256, 0, stream>>>(
        x, cen, rot, lut, out, out + (size_t)NROWS * DDIM);
}